// Round 1
// baseline (210.318 us; speedup 1.0000x reference)
//
#include <hip/hip_runtime.h>

// Problem constants (fixed by the reference)
#define T_TOKENS 16384   // B*S = 4*4096
#define HDIM     2048
#define NEXP     8
#define TPW      8       // tokens per wave
#define WAVES_PER_BLOCK 4
#define NBLOCKS  512     // 512*4 waves * 8 tokens = 16384 = T_TOKENS exactly

__device__ __forceinline__ float dot4(float4 a, float4 b) {
    return a.x * b.x + a.y * b.y + a.z * b.z + a.w * b.w;
}

// Value-splitting butterfly stage: 2*D live accumulators -> D.
// After stages 32,16,8,4,2,1 lane l holds the full cross-lane sum of acc index l.
template <int D>
__device__ __forceinline__ void reduce_stage(float* acc, int lane) {
    const bool upper = (lane & D) != 0;
#pragma unroll
    for (int i = 0; i < D; ++i) {
        float send = upper ? acc[i] : acc[i + D];
        float recv = __shfl_xor(send, D, 64);
        float keep = upper ? acc[i + D] : acc[i];
        acc[i] = keep + recv;
    }
}

__global__ __launch_bounds__(256, 2) void router_main(
    const float* __restrict__ x, const float* __restrict__ gate_w,
    float* __restrict__ out, int* __restrict__ gcnt) {
    __shared__ float lds_gate[NEXP * HDIM];  // 65536 bytes exactly

    const int tid = threadIdx.x;

    // Stage gate_w (8x2048 f32) into LDS: 4096 float4 / 256 threads = 16 each.
    const float4* g4 = (const float4*)gate_w;
    float4* l4 = (float4*)lds_gate;
#pragma unroll
    for (int i = 0; i < (NEXP * HDIM / 4) / 256; ++i)
        l4[i * 256 + tid] = g4[i * 256 + tid];
    __syncthreads();

    const int lane   = tid & 63;
    const int gwave  = blockIdx.x * WAVES_PER_BLOCK + (tid >> 6);
    const int t_base = gwave * TPW;  // exact cover of T_TOKENS

    float acc[64];  // acc[t*8+e]: partial dot of token t_base+t with expert e
#pragma unroll
    for (int v = 0; v < 64; ++v) acc[v] = 0.f;

    const float4* x4 = (const float4*)x;
    // Each chunk = 256 floats of H; lane covers 4 floats -> 8 chunks cover H=2048.
    for (int c = 0; c < HDIM / 256; ++c) {
        float4 xv[TPW];
#pragma unroll
        for (int t = 0; t < TPW; ++t)
            xv[t] = x4[(size_t)(t_base + t) * (HDIM / 4) + c * 64 + lane];
#pragma unroll
        for (int e = 0; e < NEXP; ++e) {
            float4 gv = l4[e * (HDIM / 4) + c * 64 + lane];
#pragma unroll
            for (int t = 0; t < TPW; ++t)
                acc[t * 8 + e] += dot4(xv[t], gv);
        }
    }

    reduce_stage<32>(acc, lane);
    reduce_stage<16>(acc, lane);
    reduce_stage<8>(acc, lane);
    reduce_stage<4>(acc, lane);
    reduce_stage<2>(acc, lane);
    reduce_stage<1>(acc, lane);
    const float logit = acc[0];  // lane l: token t_base+(l>>3), expert l&7

    // Every lane gathers its token-group's 8 logits (groups of 8 lanes).
    const int base = lane & ~7;
    float lg[NEXP];
#pragma unroll
    for (int e = 0; e < NEXP; ++e) lg[e] = __shfl(logit, base + e, 64);

    // top-2, lowest index wins ties (matches jax.lax.top_k)
    int i1 = 0; float m1 = lg[0];
#pragma unroll
    for (int e = 1; e < NEXP; ++e) {
        if (lg[e] > m1) { m1 = lg[e]; i1 = e; }
    }
    int i2 = 1; float m2 = -3.4e38f;
#pragma unroll
    for (int e = 0; e < NEXP; ++e) {
        if (e != i1 && lg[e] > m2) { m2 = lg[e]; i2 = e; }
    }

    // renormalized softmax over the top-2: w1 = e^l1/(e^l1+e^l2)
    const float r  = __expf(m2 - m1);  // <= 1
    const float w1 = 1.f / (1.f + r);
    const float w2 = 1.f - w1;

    const bool leader = (lane & 7) == 0;
    const int  tok    = t_base + (lane >> 3);
    if (leader) {
        out[tok * 2 + 0] = w1;
        out[tok * 2 + 1] = w2;
        out[2 * T_TOKENS + tok * 2 + 0] = (float)i1;  // indices as f32 (flat f32 out buffer)
        out[2 * T_TOKENS + tok * 2 + 1] = (float)i2;
    }

    // Per-wave expert histogram via ballot -> 8 atomics per wave (one per expert,
    // issued by 8 different lanes in one wave).
    int my_cnt = 0;
#pragma unroll
    for (int e = 0; e < NEXP; ++e) {
        unsigned long long b1 = __ballot(leader && (i1 == e));
        unsigned long long b2 = __ballot(leader && (i2 == e));
        int c = __popcll(b1) + __popcll(b2);
        if (lane == e) my_cnt = c;
    }
    if (lane < NEXP) atomicAdd(&gcnt[lane], my_cnt);
}

__global__ void router_aux(const int* __restrict__ gcnt, float* __restrict__ out) {
    if (threadIdx.x == 0) {
        float m[NEXP];
        float s = 0.f;
        for (int e = 0; e < NEXP; ++e) {
            m[e] = (float)gcnt[e] / (float)T_TOKENS;
            s += m[e];
        }
        const float mean = s / (float)NEXP;
        float var = 0.f;
        for (int e = 0; e < NEXP; ++e) {
            float d = m[e] - mean;
            var += d * d;
        }
        var /= (float)(NEXP - 1);           // unbiased (ddof=1), matches torch.var
        out[4 * T_TOKENS] = var * (float)NEXP;
    }
}

extern "C" void kernel_launch(void* const* d_in, const int* in_sizes, int n_in,
                              void* d_out, int out_size, void* d_ws, size_t ws_size,
                              hipStream_t stream) {
    const float* x  = (const float*)d_in[0];
    const float* gw = (const float*)d_in[1];
    float* out = (float*)d_out;
    int* gcnt  = (int*)d_ws;

    hipMemsetAsync(d_ws, 0, NEXP * sizeof(int), stream);
    router_main<<<NBLOCKS, 256, 0, stream>>>(x, gw, out, gcnt);
    router_aux<<<1, 64, 0, stream>>>(gcnt, out);
}